// Round 8
// baseline (410.311 us; speedup 1.0000x reference)
//
#include <hip/hip_runtime.h>
#include <hip/hip_bf16.h>

#define NN 50000
#define NE 400000
#define NF 128
#define HID 128
#define NH 4
#define HC 32
#define NC 10
#define KHOPS 3
#define NBLK ((NN + 1023) / 1024)   // 49

typedef unsigned int uint;
typedef unsigned short ushort;
typedef __attribute__((ext_vector_type(8))) short bf16x8;
typedef __attribute__((ext_vector_type(4))) float f32x4;
typedef __attribute__((ext_vector_type(2))) float f32x2;

// -------- edge dtype detect: int64 (odd words all zero) vs int32 --------
__global__ void detect_kernel(const int* __restrict__ ei, int* __restrict__ flag) {
    int w = ei[2 * threadIdx.x + 1];
    unsigned long long b = __ballot(w != 0);
    if (threadIdx.x == 0) *flag = (b == 0ULL) ? 1 : 0;  // 1 => int64
}

__device__ __forceinline__ int edge_row(const int* ei, int is64, int e) {
    return is64 ? ei[2 * e] : ei[e];
}
__device__ __forceinline__ int edge_col(const int* ei, int is64, int e) {
    return is64 ? ei[2 * NE + 2 * e] : ei[NE + e];
}

__global__ void zero_kernel(int* __restrict__ p, int n) {
    int i = blockIdx.x * blockDim.x + threadIdx.x;
    if (i < n) p[i] = 0;
}

__global__ void hist_kernel(const int* __restrict__ ei, const int* __restrict__ flag,
                            int* __restrict__ counts) {
    int e = blockIdx.x * blockDim.x + threadIdx.x;
    if (e >= NE) return;
    int c = edge_col(ei, *flag, e);
    atomicAdd(&counts[c], 1);
}

// ---- hierarchical scan ----
__global__ __launch_bounds__(256) void bsum_kernel(const int* __restrict__ counts,
                                                   int* __restrict__ bsum) {
    int b = blockIdx.x, tid = threadIdx.x;
    int base = b * 1024 + tid * 4;
    int4 v = {0, 0, 0, 0};
    if (base < NN) v = *(const int4*)(counts + base);
    int s = v.x + v.y + v.z + v.w;
#pragma unroll
    for (int off = 32; off >= 1; off >>= 1) s += __shfl_xor(s, off);
    __shared__ int ws[4];
    int lane = tid & 63, w = tid >> 6;
    if (lane == 0) ws[w] = s;
    __syncthreads();
    if (tid == 0) bsum[b] = ws[0] + ws[1] + ws[2] + ws[3];
}

__global__ void bscan_kernel(const int* __restrict__ bsum, int* __restrict__ boff,
                             int* __restrict__ rowptr) {
    int lane = threadIdx.x;
    int v = (lane < NBLK) ? bsum[lane] : 0;
    int t = v;
#pragma unroll
    for (int off = 1; off < 64; off <<= 1) {
        int u = __shfl_up(t, off);
        if (lane >= off) t += u;
    }
    if (lane < NBLK) boff[lane] = t - v;
    if (lane == NBLK - 1) rowptr[NN] = t;
}

__global__ __launch_bounds__(256) void scanb_kernel(const int* __restrict__ counts,
                                                    const int* __restrict__ boff,
                                                    int* __restrict__ rowptr,
                                                    int* __restrict__ cursor) {
    int b = blockIdx.x, tid = threadIdx.x;
    int base = b * 1024 + tid * 4;
    int4 v = {0, 0, 0, 0};
    if (base < NN) v = *(const int4*)(counts + base);
    int s3 = v.x + v.y + v.z + v.w;
    int lane = tid & 63, w = tid >> 6;
    int t = s3;
#pragma unroll
    for (int off = 1; off < 64; off <<= 1) {
        int u = __shfl_up(t, off);
        if (lane >= off) t += u;
    }
    __shared__ int ws[4];
    if (lane == 63) ws[w] = t;
    __syncthreads();
    int wofs = boff[b];
    for (int i = 0; i < 4; i++) wofs += (i < w) ? ws[i] : 0;
    int excl = wofs + t - s3;
    if (base < NN) {
        int4 o;
        o.x = excl;
        o.y = excl + v.x;
        o.z = o.y + v.y;
        o.w = o.z + v.z;
        *(int4*)(rowptr + base) = o;
        *(int4*)(cursor + base) = o;
    }
}

__global__ void scatter_kernel(const int* __restrict__ ei, const int* __restrict__ flag,
                               int* __restrict__ cursor, int* __restrict__ srows) {
    int e = blockIdx.x * blockDim.x + threadIdx.x;
    if (e >= NE) return;
    int is64 = *flag;
    int r = edge_row(ei, is64, e);
    int c = edge_col(ei, is64, e);
    int pos = atomicAdd(&cursor[c], 1);
    srows[pos] = r;
}

// -------- bf16 helpers --------
__device__ __forceinline__ short bfbits(float f) {
    __hip_bfloat16 h = __float2bfloat16(f);
    return *reinterpret_cast<short*>(&h);
}
__device__ __forceinline__ ushort bfbitsu(float f) {
    __hip_bfloat16 h = __float2bfloat16(f);
    return *reinterpret_cast<ushort*>(&h);
}
__device__ __forceinline__ float bflo(uint u) { return __uint_as_float(u << 16); }
__device__ __forceinline__ float bfhi(uint u) { return __uint_as_float(u & 0xFFFF0000u); }
__device__ __forceinline__ float bfs(ushort u) { return __uint_as_float(((uint)u) << 16); }
__device__ __forceinline__ f32x2 bf2(uint u) {
    return f32x2{__uint_as_float(u << 16), __uint_as_float(u & 0xFFFF0000u)};
}

// -------- fp8 e4m3 pack/unpack (HW cvt; word-select compile-time) --------
template<bool HI>
__device__ __forceinline__ uint pk8(float a, float b, uint old) {
    return __builtin_amdgcn_cvt_pk_fp8_f32(a, b, old, HI);
}
template<bool HI>
__device__ __forceinline__ f32x2 upk8(uint w) {
    return __builtin_amdgcn_cvt_pk_f32_fp8(w, HI);
}

// -------- weight convert: bf16, transposed [col][k] --------
__global__ void wconv_kernel(const float* __restrict__ Wt, const float* __restrict__ Wq,
                             const float* __restrict__ Wk, const float* __restrict__ Wv,
                             ushort* __restrict__ Wtb, ushort* __restrict__ Wqkvb) {
    int idx = blockIdx.x * 256 + threadIdx.x;
    if (idx < 128 * 128) {
        int c = idx >> 7, k = idx & 127;
        Wtb[c * 128 + k] = bfbitsu(Wt[k * 128 + c]);
    }
    if (idx < 304 * 128) {
        int c = idx >> 7, k = idx & 127;
        float w;
        if (c < 128) w = Wq[k * 128 + c];
        else if (c < 256) w = Wk[k * 128 + (c - 128)];
        else { int cv = c - 256; w = (cv < 40) ? Wv[k * 40 + cv] : 0.f; }
        Wqkvb[c * 128 + k] = bfbitsu(w);
    }
}

// -------- x = relu(nf @ Wt + bt), MFMA, column-split over gridDim.y --------
__global__ __launch_bounds__(256) void xm_kernel(const float* __restrict__ nf,
                                                 const ushort* __restrict__ Wtb,
                                                 const float* __restrict__ bt,
                                                 ushort* __restrict__ xb) {
    int wid = threadIdx.x >> 6, lane = threadIdx.x & 63;
    int row0 = blockIdx.x * 64 + wid * 16;
    int r = lane & 15, kg = lane >> 4;
    int ar = row0 + r;
    if (ar > NN - 1) ar = NN - 1;
    int ctbeg = blockIdx.y * 4;
    f32x4 acc[4];
#pragma unroll
    for (int ct = 0; ct < 4; ct++) acc[ct] = f32x4{0.f, 0.f, 0.f, 0.f};
#pragma unroll
    for (int ks = 0; ks < 4; ks++) {
        int k0 = ks * 32 + kg * 8;
        const float4* ap = (const float4*)(nf + (size_t)ar * 128 + k0);
        float4 a0 = ap[0], a1 = ap[1];
        bf16x8 af;
        af[0] = bfbits(a0.x); af[1] = bfbits(a0.y); af[2] = bfbits(a0.z); af[3] = bfbits(a0.w);
        af[4] = bfbits(a1.x); af[5] = bfbits(a1.y); af[6] = bfbits(a1.z); af[7] = bfbits(a1.w);
#pragma unroll
        for (int ct = 0; ct < 4; ct++) {
            bf16x8 bfr = *(const bf16x8*)(Wtb + (size_t)((ctbeg + ct) * 16 + r) * 128 + k0);
            acc[ct] = __builtin_amdgcn_mfma_f32_16x16x32_bf16(af, bfr, acc[ct], 0, 0, 0);
        }
    }
#pragma unroll
    for (int ct = 0; ct < 4; ct++) {
        int c = (ctbeg + ct) * 16 + r;
        float b = bt[c];
#pragma unroll
        for (int reg = 0; reg < 4; reg++) {
            int n = row0 + kg * 4 + reg;
            if (n < NN) {
                float z = acc[ct][reg] + b;
                xb[(size_t)n * 128 + c] = bfbitsu(fmaxf(z, 0.f));
            }
        }
    }
}

// -------- fused QKV; Q -> Qp f32 [n][128], K -> K0/16 fp8 [n][128], V -> bf16 [n][4][16] --------
template<int CTBEG, int NCT>
__device__ __forceinline__ void qkv_body(const ushort* __restrict__ xb,
                                         const ushort* __restrict__ Wqkvb,
                                         const float* __restrict__ bq,
                                         const float* __restrict__ bk,
                                         const float* __restrict__ bv,
                                         float* __restrict__ Qp,
                                         unsigned char* __restrict__ K8,
                                         ushort* __restrict__ Vbf,
                                         int row0, int r, int kg) {
    int ar = row0 + r;
    if (ar > NN - 1) ar = NN - 1;
    f32x4 acc[NCT];
#pragma unroll
    for (int ct = 0; ct < NCT; ct++) acc[ct] = f32x4{0.f, 0.f, 0.f, 0.f};
#pragma unroll
    for (int ks = 0; ks < 4; ks++) {
        int k0 = ks * 32 + kg * 8;
        bf16x8 af = *(const bf16x8*)(xb + (size_t)ar * 128 + k0);
#pragma unroll
        for (int ct = 0; ct < NCT; ct++) {
            bf16x8 bfr = *(const bf16x8*)(Wqkvb + (size_t)((CTBEG + ct) * 16 + r) * 128 + k0);
            acc[ct] = __builtin_amdgcn_mfma_f32_16x16x32_bf16(af, bfr, acc[ct], 0, 0, 0);
        }
    }
#pragma unroll
    for (int ct = 0; ct < NCT; ct++) {
        int c = (CTBEG + ct) * 16 + r;
        float bias;
        if (c < 128) bias = bq[c];
        else if (c < 256) bias = bk[c - 128];
        else { int cv = c - 256; bias = (cv < 40) ? bv[cv] : 0.f; }
#pragma unroll
        for (int reg = 0; reg < 4; reg++) {
            int n = row0 + kg * 4 + reg;
            if (n >= NN) continue;
            float z = acc[ct][reg] + bias;
            if (c < 128) {
                float q = z > 0.f ? 1.f + z : __expf(z);
                Qp[(size_t)n * 128 + c] = q;
            } else if (c < 256) {
                int cc = c - 128;
                float kv = (z > 0.f ? 1.f + z : __expf(z)) * 0.0625f;  // K0/16
                uint w = pk8<false>(kv, 0.f, 0u);
                K8[(size_t)n * 128 + cc] = (unsigned char)(w & 0xFF);
            } else {
                int cv = c - 256;
                if (cv < 40) {
                    int hh = cv / 10, cc = cv - hh * 10;
                    Vbf[(size_t)n * 64 + hh * 16 + cc] = bfbitsu(z);
                }
            }
        }
    }
}

__global__ __launch_bounds__(256) void qkv_kernel(const ushort* __restrict__ xb,
                                                  const ushort* __restrict__ Wqkvb,
                                                  const float* __restrict__ bq,
                                                  const float* __restrict__ bk,
                                                  const float* __restrict__ bv,
                                                  float* __restrict__ Qp,
                                                  unsigned char* __restrict__ K8,
                                                  ushort* __restrict__ Vbf) {
    int wid = threadIdx.x >> 6, lane = threadIdx.x & 63;
    int row0 = blockIdx.x * 64 + wid * 16;
    int r = lane & 15, kg = lane >> 4;
    if (blockIdx.y == 0)
        qkv_body<0, 8>(xb, Wqkvb, bq, bk, bv, Qp, K8, Vbf, row0, r, kg);
    else if (blockIdx.y == 1)
        qkv_body<8, 8>(xb, Wqkvb, bq, bk, bv, Qp, K8, Vbf, row0, r, kg);
    else
        qkv_body<16, 3>(xb, Wqkvb, bq, bk, bv, Qp, K8, Vbf, row0, r, kg);
}

// -------- out init: out[n,c] = hopwise[0] * sum_h V[n,h,c] --------
__global__ void vinit_kernel(float* __restrict__ out, const ushort* __restrict__ Vbf,
                             const float* __restrict__ hopwise) {
    int idx = blockIdx.x * blockDim.x + threadIdx.x;
    if (idx >= NN * NC) return;
    int n = idx / NC, c = idx - n * NC;
    const ushort* v = Vbf + (size_t)n * 64 + c;
    out[idx] = hopwise[0] * (bfs(v[0]) + bfs(v[16]) + bfs(v[32]) + bfs(v[48]));
}

// -------- fused all-head epilog. All state at 1/16 scale; CST' = 1e-5/16. --------
__device__ __forceinline__ void fused_epilog(f32x2 A0[5], f32x2 A1[5], f32x2 kA,
                                             int gw, int lane,
                                             const float* __restrict__ Qp,
                                             float* __restrict__ out,
                                             uint4* __restrict__ Mq4n, uint* __restrict__ Mrun,
                                             ushort* __restrict__ K8n,
                                             const float* __restrict__ hopwise,
                                             const float* __restrict__ headwise,
                                             int hop, int write_next) {
    int p0 = lane * 2;
    float2 q = *(const float2*)(Qp + (size_t)gw * 128 + p0);
    float num[10];
#pragma unroll
    for (int j = 0; j < 5; j++) {
        num[2 * j] = q.x * A0[j].x + q.y * A1[j].x;
        num[2 * j + 1] = q.x * A0[j].y + q.y * A1[j].y;
    }
    float den = q.x * kA.x + q.y * kA.y;
#pragma unroll
    for (int off = 8; off >= 1; off >>= 1) {
#pragma unroll
        for (int c = 0; c < 10; c++) num[c] += __shfl_xor(num[c], off);
        den += __shfl_xor(den, off);
    }
    float e0 = __expf(headwise[0 * KHOPS + hop]);
    float e1 = __expf(headwise[1 * KHOPS + hop]);
    float e2 = __expf(headwise[2 * KHOPS + hop]);
    float e3 = __expf(headwise[3 * KHOPS + hop]);
    int h = lane >> 4;
    float eh = (h == 0) ? e0 : (h == 1) ? e1 : (h == 2) ? e2 : e3;
    float gamma = hopwise[hop + 1] * eh / (e0 + e1 + e2 + e3);
    float s = gamma / (den + 6.25e-7f);
    float tot[10];
#pragma unroll
    for (int c = 0; c < 10; c++) {
        tot[c] = s * num[c];
        tot[c] += __shfl_xor(tot[c], 16);
        tot[c] += __shfl_xor(tot[c], 32);
    }
    if (lane < 10) {
        float v = lane == 0 ? tot[0] : lane == 1 ? tot[1] : lane == 2 ? tot[2] :
                  lane == 3 ? tot[3] : lane == 4 ? tot[4] : lane == 5 ? tot[5] :
                  lane == 6 ? tot[6] : lane == 7 ? tot[7] : lane == 8 ? tot[8] : tot[9];
        out[(size_t)gw * 10 + lane] += v;
    }
    if (write_next) {
        uint4 o;
        o.x = pk8<true>(A0[1].x, A0[1].y, pk8<false>(A0[0].x, A0[0].y, 0u));
        o.y = pk8<true>(A0[3].x, A0[3].y, pk8<false>(A0[2].x, A0[2].y, 0u));
        o.z = pk8<true>(A1[1].x, A1[1].y, pk8<false>(A1[0].x, A1[0].y, 0u));
        o.w = pk8<true>(A1[3].x, A1[3].y, pk8<false>(A1[2].x, A1[2].y, 0u));
        Mq4n[(size_t)gw * 64 + lane] = o;
        Mrun[(size_t)gw * 64 + lane] =
            pk8<true>(A1[4].x, A1[4].y, pk8<false>(A0[4].x, A0[4].y, 0u));
        uint kw = pk8<false>(kA.x, kA.y, 0u);
        K8n[(size_t)gw * 64 + lane] = (ushort)(kw & 0xFFFF);
    }
}

// -------- per-edge fp8 accumulate (packed f32x2) --------
__device__ __forceinline__ void edge_acc(f32x2 A0[5], f32x2 A1[5], f32x2& kA,
                                         uint4 mq, uint mr, uint kk) {
    A0[0] += upk8<false>(mq.x);
    A0[1] += upk8<true>(mq.x);
    A0[2] += upk8<false>(mq.y);
    A0[3] += upk8<true>(mq.y);
    A1[0] += upk8<false>(mq.z);
    A1[1] += upk8<true>(mq.z);
    A1[2] += upk8<false>(mq.w);
    A1[3] += upk8<true>(mq.w);
    A0[4] += upk8<false>(mr);
    A1[4] += upk8<true>(mr);
    kA += upk8<false>(kk);
}

// -------- fused hop 0: all heads; gather fp8 K0 row + per-head bf16 V row --------
__global__ __launch_bounds__(256) void aggf0_kernel(const ushort* __restrict__ K8c,
                                                    const ushort* __restrict__ Vbf,
                                                    const float* __restrict__ Qp,
                                                    float* __restrict__ out,
                                                    uint4* __restrict__ Mq4n, uint* __restrict__ Mrun,
                                                    ushort* __restrict__ K8n,
                                                    const int* __restrict__ rowptr,
                                                    const int* __restrict__ srows,
                                                    const float* __restrict__ hopwise,
                                                    const float* __restrict__ headwise) {
    int gw = (blockIdx.x * 256 + threadIdx.x) >> 6;
    int lane = threadIdx.x & 63;
    int h = lane >> 4;
    int beg = rowptr[gw], end = rowptr[gw + 1];
    f32x2 A0[5], A1[5], kA = f32x2{0.f, 0.f};
#pragma unroll
    for (int j = 0; j < 5; j++) { A0[j] = f32x2{0.f, 0.f}; A1[j] = f32x2{0.f, 0.f}; }
    int e = beg;
    for (; e + 1 < end; e += 2) {
        int s0 = srows[e], s1 = srows[e + 1];
        uint k0w = K8c[(size_t)s0 * 64 + lane];
        uint k1w = K8c[(size_t)s1 * 64 + lane];
        const ushort* vb0 = Vbf + (size_t)s0 * 64 + h * 16;
        const ushort* vb1 = Vbf + (size_t)s1 * 64 + h * 16;
        uint4 v40 = *(const uint4*)vb0; uint v10 = *(const uint*)(vb0 + 8);
        uint4 v41 = *(const uint4*)vb1; uint v11 = *(const uint*)(vb1 + 8);
        f32x2 kk0 = upk8<false>(k0w);   // {K0/16 p0, K0/16 p1}
        f32x2 kk1 = upk8<false>(k1w);
        kA += kk0 + kk1;
        f32x2 V0[5] = {bf2(v40.x), bf2(v40.y), bf2(v40.z), bf2(v40.w), bf2(v10)};
        f32x2 V1[5] = {bf2(v41.x), bf2(v41.y), bf2(v41.z), bf2(v41.w), bf2(v11)};
        f32x2 k00 = f32x2{kk0.x, kk0.x}, k01 = f32x2{kk0.y, kk0.y};
        f32x2 k10 = f32x2{kk1.x, kk1.x}, k11 = f32x2{kk1.y, kk1.y};
#pragma unroll
        for (int j = 0; j < 5; j++) {
            A0[j] += k00 * V0[j] + k10 * V1[j];
            A1[j] += k01 * V0[j] + k11 * V1[j];
        }
    }
    for (; e < end; ++e) {
        int s0 = srows[e];
        uint k0w = K8c[(size_t)s0 * 64 + lane];
        const ushort* vb0 = Vbf + (size_t)s0 * 64 + h * 16;
        uint4 v40 = *(const uint4*)vb0; uint v10 = *(const uint*)(vb0 + 8);
        f32x2 kk0 = upk8<false>(k0w);
        kA += kk0;
        f32x2 V0[5] = {bf2(v40.x), bf2(v40.y), bf2(v40.z), bf2(v40.w), bf2(v10)};
        f32x2 k00 = f32x2{kk0.x, kk0.x}, k01 = f32x2{kk0.y, kk0.y};
#pragma unroll
        for (int j = 0; j < 5; j++) {
            A0[j] += k00 * V0[j];
            A1[j] += k01 * V0[j];
        }
    }
    fused_epilog(A0, A1, kA, gw, lane, Qp, out, Mq4n, Mrun, K8n,
                 hopwise, headwise, 0, 1);
}

// -------- fused hops >=1: per edge uint4 (M c0-7) + uint (M c8-9) + ushort (K) --------
__global__ __launch_bounds__(256) void aggf_kernel(const uint4* __restrict__ Mq4,
                                                   const uint* __restrict__ Mru,
                                                   const ushort* __restrict__ K8c,
                                                   const float* __restrict__ Qp,
                                                   float* __restrict__ out,
                                                   uint4* __restrict__ Mq4n, uint* __restrict__ Mrun,
                                                   ushort* __restrict__ K8n,
                                                   const int* __restrict__ rowptr,
                                                   const int* __restrict__ srows,
                                                   const float* __restrict__ hopwise,
                                                   const float* __restrict__ headwise,
                                                   int hop, int write_next) {
    int gw = (blockIdx.x * 256 + threadIdx.x) >> 6;
    int lane = threadIdx.x & 63;
    int beg = rowptr[gw], end = rowptr[gw + 1];
    f32x2 A0[5], A1[5], kA = f32x2{0.f, 0.f};
#pragma unroll
    for (int j = 0; j < 5; j++) { A0[j] = f32x2{0.f, 0.f}; A1[j] = f32x2{0.f, 0.f}; }
    int e = beg;
    for (; e + 5 < end; e += 6) {
        int s0 = srows[e], s1 = srows[e + 1], s2 = srows[e + 2];
        int s3 = srows[e + 3], s4 = srows[e + 4], s5 = srows[e + 5];
        uint4 m0 = Mq4[(size_t)s0 * 64 + lane];
        uint4 m1 = Mq4[(size_t)s1 * 64 + lane];
        uint4 m2 = Mq4[(size_t)s2 * 64 + lane];
        uint4 m3 = Mq4[(size_t)s3 * 64 + lane];
        uint4 m4 = Mq4[(size_t)s4 * 64 + lane];
        uint4 m5 = Mq4[(size_t)s5 * 64 + lane];
        uint r0 = Mru[(size_t)s0 * 64 + lane];
        uint r1 = Mru[(size_t)s1 * 64 + lane];
        uint r2 = Mru[(size_t)s2 * 64 + lane];
        uint r3 = Mru[(size_t)s3 * 64 + lane];
        uint r4 = Mru[(size_t)s4 * 64 + lane];
        uint r5 = Mru[(size_t)s5 * 64 + lane];
        uint k0 = K8c[(size_t)s0 * 64 + lane];
        uint k1 = K8c[(size_t)s1 * 64 + lane];
        uint k2 = K8c[(size_t)s2 * 64 + lane];
        uint k3 = K8c[(size_t)s3 * 64 + lane];
        uint k4 = K8c[(size_t)s4 * 64 + lane];
        uint k5 = K8c[(size_t)s5 * 64 + lane];
        edge_acc(A0, A1, kA, m0, r0, k0);
        edge_acc(A0, A1, kA, m1, r1, k1);
        edge_acc(A0, A1, kA, m2, r2, k2);
        edge_acc(A0, A1, kA, m3, r3, k3);
        edge_acc(A0, A1, kA, m4, r4, k4);
        edge_acc(A0, A1, kA, m5, r5, k5);
    }
    for (; e < end; ++e) {
        int s0 = srows[e];
        uint4 m0 = Mq4[(size_t)s0 * 64 + lane];
        uint r0 = Mru[(size_t)s0 * 64 + lane];
        uint k0 = K8c[(size_t)s0 * 64 + lane];
        edge_acc(A0, A1, kA, m0, r0, k0);
    }
    fused_epilog(A0, A1, kA, gw, lane, Qp, out, Mq4n, Mrun, K8n,
                 hopwise, headwise, hop, write_next);
}

extern "C" void kernel_launch(void* const* d_in, const int* in_sizes, int n_in,
                              void* d_out, int out_size, void* d_ws, size_t ws_size,
                              hipStream_t stream) {
    const float* nf = (const float*)d_in[0];
    const int* ei = (const int*)d_in[1];
    const float* Wt = (const float*)d_in[2];
    const float* bt = (const float*)d_in[3];
    const float* Wq = (const float*)d_in[4];
    const float* bq = (const float*)d_in[5];
    const float* Wk = (const float*)d_in[6];
    const float* bk = (const float*)d_in[7];
    const float* Wv = (const float*)d_in[8];
    const float* bv = (const float*)d_in[9];
    const float* hopwise = (const float*)d_in[10];
    const float* headwise = (const float*)d_in[11];
    float* out = (float*)d_out;

    char* p = (char*)d_ws;
    auto alloc = [&](size_t bytes) {
        char* r = p;
        p += (bytes + 255) & ~(size_t)255;
        return r;
    };
    int* rowptr = (int*)alloc((NN + 4) * sizeof(int));
    int* cursor = (int*)alloc((NN + 4) * sizeof(int));
    int* bsum = (int*)alloc(NBLK * sizeof(int));
    int* boff = (int*)alloc(NBLK * sizeof(int));
    int* srows = (int*)alloc((size_t)NE * sizeof(int));
    int* flag = (int*)alloc(sizeof(int));
    ushort* Wtb = (ushort*)alloc(128 * 128 * sizeof(ushort));
    ushort* Wqkvb = (ushort*)alloc(304 * 128 * sizeof(ushort));
    float* Qp = (float*)alloc((size_t)NN * 128 * sizeof(float));             // 25.6 MB
    unsigned char* K8pp = (unsigned char*)alloc((size_t)NN * 128);           // 6.4 MB (K0/16 fp8)
    ushort* Vbf = (ushort*)alloc((size_t)NN * 64 * sizeof(ushort));          // 6.4 MB
    ushort* K8a = (ushort*)alloc((size_t)NN * 64 * sizeof(ushort));          // 6.4 MB (K1/16)
    uint4* Mq4a = (uint4*)alloc((size_t)NN * 64 * sizeof(uint4));            // 51.2 MB
    uint4* Mq4b = (uint4*)alloc((size_t)NN * 64 * sizeof(uint4));            // 51.2 MB
    uint* Mrua = (uint*)alloc((size_t)NN * 64 * sizeof(uint));               // 12.8 MB
    uint* Mrub = (uint*)alloc((size_t)NN * 64 * sizeof(uint));               // 12.8 MB
    // total ~176 MB. aliases over dead regions:
    ushort* xb = (ushort*)Mq4a;        // x bf16 dead before aggf0 writes Mq4a
    ushort* K8b = (ushort*)K8pp;       // K2 overwrites K0 (K0 last read by aggf0)

    detect_kernel<<<1, 64, 0, stream>>>(ei, flag);
    zero_kernel<<<(NN + 255) / 256, 256, 0, stream>>>(cursor, NN);
    hist_kernel<<<(NE + 255) / 256, 256, 0, stream>>>(ei, flag, cursor);
    bsum_kernel<<<NBLK, 256, 0, stream>>>(cursor, bsum);
    bscan_kernel<<<1, 64, 0, stream>>>(bsum, boff, rowptr);
    scanb_kernel<<<NBLK, 256, 0, stream>>>(cursor, boff, rowptr, cursor);
    scatter_kernel<<<(NE + 255) / 256, 256, 0, stream>>>(ei, flag, cursor, srows);

    wconv_kernel<<<(304 * 128 + 255) / 256, 256, 0, stream>>>(Wt, Wq, Wk, Wv, Wtb, Wqkvb);
    int nrb = (NN + 63) / 64;
    xm_kernel<<<dim3(nrb, 2), 256, 0, stream>>>(nf, Wtb, bt, xb);
    qkv_kernel<<<dim3(nrb, 3), 256, 0, stream>>>(xb, Wqkvb, bq, bk, bv, Qp, K8pp, Vbf);
    vinit_kernel<<<(NN * NC + 255) / 256, 256, 0, stream>>>(out, Vbf, hopwise);

    // hop 0: (K0/16, V) -> M1/16, K1/16 ; hop 1: -> M2/16, K2/16 ; hop 2: -> out only
    aggf0_kernel<<<NN / 4, 256, 0, stream>>>((const ushort*)K8pp, Vbf, Qp, out,
                                             Mq4a, Mrua, K8a,
                                             rowptr, srows, hopwise, headwise);
    aggf_kernel<<<NN / 4, 256, 0, stream>>>(Mq4a, Mrua, K8a, Qp, out, Mq4b, Mrub, K8b,
                                            rowptr, srows, hopwise, headwise, 1, 1);
    aggf_kernel<<<NN / 4, 256, 0, stream>>>(Mq4b, Mrub, K8b, Qp, out, Mq4a, Mrua, K8a,
                                            rowptr, srows, hopwise, headwise, 2, 0);
}

// Round 9
// 376.588 us; speedup vs baseline: 1.0895x; 1.0895x over previous
//
#include <hip/hip_runtime.h>
#include <hip/hip_bf16.h>

#define NN 50000
#define NE 400000
#define NF 128
#define HID 128
#define NH 4
#define HC 32
#define NC 10
#define KHOPS 3
#define NBLK ((NN + 1023) / 1024)   // 49

typedef unsigned int uint;
typedef unsigned short ushort;
typedef __attribute__((ext_vector_type(8))) short bf16x8;
typedef __attribute__((ext_vector_type(4))) float f32x4;
typedef __attribute__((ext_vector_type(2))) float f32x2;

// -------- edge dtype detect: int64 (odd words all zero) vs int32 --------
__global__ void detect_kernel(const int* __restrict__ ei, int* __restrict__ flag) {
    int w = ei[2 * threadIdx.x + 1];
    unsigned long long b = __ballot(w != 0);
    if (threadIdx.x == 0) *flag = (b == 0ULL) ? 1 : 0;  // 1 => int64
}

__device__ __forceinline__ int edge_row(const int* ei, int is64, int e) {
    return is64 ? ei[2 * e] : ei[e];
}
__device__ __forceinline__ int edge_col(const int* ei, int is64, int e) {
    return is64 ? ei[2 * NE + 2 * e] : ei[NE + e];
}

__global__ void zero_kernel(int* __restrict__ p, int n) {
    int i = blockIdx.x * blockDim.x + threadIdx.x;
    if (i < n) p[i] = 0;
}

__global__ void hist_kernel(const int* __restrict__ ei, const int* __restrict__ flag,
                            int* __restrict__ counts) {
    int e = blockIdx.x * blockDim.x + threadIdx.x;
    if (e >= NE) return;
    int c = edge_col(ei, *flag, e);
    atomicAdd(&counts[c], 1);
}

// ---- hierarchical scan ----
__global__ __launch_bounds__(256) void bsum_kernel(const int* __restrict__ counts,
                                                   int* __restrict__ bsum) {
    int b = blockIdx.x, tid = threadIdx.x;
    int base = b * 1024 + tid * 4;
    int4 v = {0, 0, 0, 0};
    if (base < NN) v = *(const int4*)(counts + base);
    int s = v.x + v.y + v.z + v.w;
#pragma unroll
    for (int off = 32; off >= 1; off >>= 1) s += __shfl_xor(s, off);
    __shared__ int ws[4];
    int lane = tid & 63, w = tid >> 6;
    if (lane == 0) ws[w] = s;
    __syncthreads();
    if (tid == 0) bsum[b] = ws[0] + ws[1] + ws[2] + ws[3];
}

__global__ void bscan_kernel(const int* __restrict__ bsum, int* __restrict__ boff,
                             int* __restrict__ rowptr) {
    int lane = threadIdx.x;
    int v = (lane < NBLK) ? bsum[lane] : 0;
    int t = v;
#pragma unroll
    for (int off = 1; off < 64; off <<= 1) {
        int u = __shfl_up(t, off);
        if (lane >= off) t += u;
    }
    if (lane < NBLK) boff[lane] = t - v;
    if (lane == NBLK - 1) rowptr[NN] = t;
}

__global__ __launch_bounds__(256) void scanb_kernel(const int* __restrict__ counts,
                                                    const int* __restrict__ boff,
                                                    int* __restrict__ rowptr,
                                                    int* __restrict__ cursor) {
    int b = blockIdx.x, tid = threadIdx.x;
    int base = b * 1024 + tid * 4;
    int4 v = {0, 0, 0, 0};
    if (base < NN) v = *(const int4*)(counts + base);
    int s3 = v.x + v.y + v.z + v.w;
    int lane = tid & 63, w = tid >> 6;
    int t = s3;
#pragma unroll
    for (int off = 1; off < 64; off <<= 1) {
        int u = __shfl_up(t, off);
        if (lane >= off) t += u;
    }
    __shared__ int ws[4];
    if (lane == 63) ws[w] = t;
    __syncthreads();
    int wofs = boff[b];
    for (int i = 0; i < 4; i++) wofs += (i < w) ? ws[i] : 0;
    int excl = wofs + t - s3;
    if (base < NN) {
        int4 o;
        o.x = excl;
        o.y = excl + v.x;
        o.z = o.y + v.y;
        o.w = o.z + v.z;
        *(int4*)(rowptr + base) = o;
        *(int4*)(cursor + base) = o;
    }
}

__global__ void scatter_kernel(const int* __restrict__ ei, const int* __restrict__ flag,
                               int* __restrict__ cursor, int* __restrict__ srows) {
    int e = blockIdx.x * blockDim.x + threadIdx.x;
    if (e >= NE) return;
    int is64 = *flag;
    int r = edge_row(ei, is64, e);
    int c = edge_col(ei, is64, e);
    int pos = atomicAdd(&cursor[c], 1);
    srows[pos] = r;
}

// -------- bf16 helpers --------
__device__ __forceinline__ short bfbits(float f) {
    __hip_bfloat16 h = __float2bfloat16(f);
    return *reinterpret_cast<short*>(&h);
}
__device__ __forceinline__ ushort bfbitsu(float f) {
    __hip_bfloat16 h = __float2bfloat16(f);
    return *reinterpret_cast<ushort*>(&h);
}
__device__ __forceinline__ float bfs(ushort u) { return __uint_as_float(((uint)u) << 16); }
__device__ __forceinline__ f32x2 bf2(uint u) {
    return f32x2{__uint_as_float(u << 16), __uint_as_float(u & 0xFFFF0000u)};
}

// -------- fp8 e4m3 pack/unpack (HW cvt; word-select compile-time) --------
template<bool HI>
__device__ __forceinline__ uint pk8(float a, float b, uint old) {
    return __builtin_amdgcn_cvt_pk_fp8_f32(a, b, old, HI);
}
template<bool HI>
__device__ __forceinline__ f32x2 upk8(uint w) {
    return __builtin_amdgcn_cvt_pk_f32_fp8(w, HI);
}

// -------- weight convert: bf16, transposed [col][k] --------
__global__ void wconv_kernel(const float* __restrict__ Wt, const float* __restrict__ Wq,
                             const float* __restrict__ Wk, const float* __restrict__ Wv,
                             ushort* __restrict__ Wtb, ushort* __restrict__ Wqkvb) {
    int idx = blockIdx.x * 256 + threadIdx.x;
    if (idx < 128 * 128) {
        int c = idx >> 7, k = idx & 127;
        Wtb[c * 128 + k] = bfbitsu(Wt[k * 128 + c]);
    }
    if (idx < 304 * 128) {
        int c = idx >> 7, k = idx & 127;
        float w;
        if (c < 128) w = Wq[k * 128 + c];
        else if (c < 256) w = Wk[k * 128 + (c - 128)];
        else { int cv = c - 256; w = (cv < 40) ? Wv[k * 40 + cv] : 0.f; }
        Wqkvb[c * 128 + k] = bfbitsu(w);
    }
}

// -------- x = relu(nf @ Wt + bt), MFMA, column-split over gridDim.y --------
__global__ __launch_bounds__(256) void xm_kernel(const float* __restrict__ nf,
                                                 const ushort* __restrict__ Wtb,
                                                 const float* __restrict__ bt,
                                                 ushort* __restrict__ xb) {
    int wid = threadIdx.x >> 6, lane = threadIdx.x & 63;
    int row0 = blockIdx.x * 64 + wid * 16;
    int r = lane & 15, kg = lane >> 4;
    int ar = row0 + r;
    if (ar > NN - 1) ar = NN - 1;
    int ctbeg = blockIdx.y * 4;
    f32x4 acc[4];
#pragma unroll
    for (int ct = 0; ct < 4; ct++) acc[ct] = f32x4{0.f, 0.f, 0.f, 0.f};
#pragma unroll
    for (int ks = 0; ks < 4; ks++) {
        int k0 = ks * 32 + kg * 8;
        const float4* ap = (const float4*)(nf + (size_t)ar * 128 + k0);
        float4 a0 = ap[0], a1 = ap[1];
        bf16x8 af;
        af[0] = bfbits(a0.x); af[1] = bfbits(a0.y); af[2] = bfbits(a0.z); af[3] = bfbits(a0.w);
        af[4] = bfbits(a1.x); af[5] = bfbits(a1.y); af[6] = bfbits(a1.z); af[7] = bfbits(a1.w);
#pragma unroll
        for (int ct = 0; ct < 4; ct++) {
            bf16x8 bfr = *(const bf16x8*)(Wtb + (size_t)((ctbeg + ct) * 16 + r) * 128 + k0);
            acc[ct] = __builtin_amdgcn_mfma_f32_16x16x32_bf16(af, bfr, acc[ct], 0, 0, 0);
        }
    }
#pragma unroll
    for (int ct = 0; ct < 4; ct++) {
        int c = (ctbeg + ct) * 16 + r;
        float b = bt[c];
#pragma unroll
        for (int reg = 0; reg < 4; reg++) {
            int n = row0 + kg * 4 + reg;
            if (n < NN) {
                float z = acc[ct][reg] + b;
                xb[(size_t)n * 128 + c] = bfbitsu(fmaxf(z, 0.f));
            }
        }
    }
}

// -------- fused QKV; Q -> Qp f32 [n][128], K -> K0/16 fp8 [n][128], V -> bf16 [n][4][16] --------
template<int CTBEG, int NCT>
__device__ __forceinline__ void qkv_body(const ushort* __restrict__ xb,
                                         const ushort* __restrict__ Wqkvb,
                                         const float* __restrict__ bq,
                                         const float* __restrict__ bk,
                                         const float* __restrict__ bv,
                                         float* __restrict__ Qp,
                                         unsigned char* __restrict__ K8,
                                         ushort* __restrict__ Vbf,
                                         int row0, int r, int kg) {
    int ar = row0 + r;
    if (ar > NN - 1) ar = NN - 1;
    f32x4 acc[NCT];
#pragma unroll
    for (int ct = 0; ct < NCT; ct++) acc[ct] = f32x4{0.f, 0.f, 0.f, 0.f};
#pragma unroll
    for (int ks = 0; ks < 4; ks++) {
        int k0 = ks * 32 + kg * 8;
        bf16x8 af = *(const bf16x8*)(xb + (size_t)ar * 128 + k0);
#pragma unroll
        for (int ct = 0; ct < NCT; ct++) {
            bf16x8 bfr = *(const bf16x8*)(Wqkvb + (size_t)((CTBEG + ct) * 16 + r) * 128 + k0);
            acc[ct] = __builtin_amdgcn_mfma_f32_16x16x32_bf16(af, bfr, acc[ct], 0, 0, 0);
        }
    }
#pragma unroll
    for (int ct = 0; ct < NCT; ct++) {
        int c = (CTBEG + ct) * 16 + r;
        float bias;
        if (c < 128) bias = bq[c];
        else if (c < 256) bias = bk[c - 128];
        else { int cv = c - 256; bias = (cv < 40) ? bv[cv] : 0.f; }
#pragma unroll
        for (int reg = 0; reg < 4; reg++) {
            int n = row0 + kg * 4 + reg;
            if (n >= NN) continue;
            float z = acc[ct][reg] + bias;
            if (c < 128) {
                float q = z > 0.f ? 1.f + z : __expf(z);
                Qp[(size_t)n * 128 + c] = q;
            } else if (c < 256) {
                int cc = c - 128;
                float kv = (z > 0.f ? 1.f + z : __expf(z)) * 0.0625f;  // K0/16
                uint w = pk8<false>(kv, 0.f, 0u);
                K8[(size_t)n * 128 + cc] = (unsigned char)(w & 0xFF);
            } else {
                int cv = c - 256;
                if (cv < 40) {
                    int hh = cv / 10, cc = cv - hh * 10;
                    Vbf[(size_t)n * 64 + hh * 16 + cc] = bfbitsu(z);
                }
            }
        }
    }
}

__global__ __launch_bounds__(256) void qkv_kernel(const ushort* __restrict__ xb,
                                                  const ushort* __restrict__ Wqkvb,
                                                  const float* __restrict__ bq,
                                                  const float* __restrict__ bk,
                                                  const float* __restrict__ bv,
                                                  float* __restrict__ Qp,
                                                  unsigned char* __restrict__ K8,
                                                  ushort* __restrict__ Vbf) {
    int wid = threadIdx.x >> 6, lane = threadIdx.x & 63;
    int row0 = blockIdx.x * 64 + wid * 16;
    int r = lane & 15, kg = lane >> 4;
    if (blockIdx.y == 0)
        qkv_body<0, 8>(xb, Wqkvb, bq, bk, bv, Qp, K8, Vbf, row0, r, kg);
    else if (blockIdx.y == 1)
        qkv_body<8, 8>(xb, Wqkvb, bq, bk, bv, Qp, K8, Vbf, row0, r, kg);
    else
        qkv_body<16, 3>(xb, Wqkvb, bq, bk, bv, Qp, K8, Vbf, row0, r, kg);
}

// -------- fused all-head epilog. All state at 1/16 scale; CST' = 1e-5/16. --------
// is_hop0: also fold the vinit term (hopwise[0]*sum_h V) and WRITE out (not RMW).
__device__ __forceinline__ void fused_epilog(f32x2 A0[5], f32x2 A1[5], f32x2 kA,
                                             int gw, int lane,
                                             const float* __restrict__ Qp,
                                             float* __restrict__ out,
                                             uint4* __restrict__ Mq4n, uint* __restrict__ Mrun,
                                             ushort* __restrict__ K8n,
                                             const float* __restrict__ hopwise,
                                             const float* __restrict__ headwise,
                                             const ushort* __restrict__ Vbf_all,
                                             int hop, int write_next, int is_hop0) {
    int p0 = lane * 2;
    float2 q = *(const float2*)(Qp + (size_t)gw * 128 + p0);
    float num[10];
#pragma unroll
    for (int j = 0; j < 5; j++) {
        num[2 * j] = q.x * A0[j].x + q.y * A1[j].x;
        num[2 * j + 1] = q.x * A0[j].y + q.y * A1[j].y;
    }
    float den = q.x * kA.x + q.y * kA.y;
#pragma unroll
    for (int off = 8; off >= 1; off >>= 1) {
#pragma unroll
        for (int c = 0; c < 10; c++) num[c] += __shfl_xor(num[c], off);
        den += __shfl_xor(den, off);
    }
    float e0 = __expf(headwise[0 * KHOPS + hop]);
    float e1 = __expf(headwise[1 * KHOPS + hop]);
    float e2 = __expf(headwise[2 * KHOPS + hop]);
    float e3 = __expf(headwise[3 * KHOPS + hop]);
    int h = lane >> 4;
    float eh = (h == 0) ? e0 : (h == 1) ? e1 : (h == 2) ? e2 : e3;
    float gamma = hopwise[hop + 1] * eh / (e0 + e1 + e2 + e3);
    float s = gamma / (den + 6.25e-7f);
    float tot[10];
#pragma unroll
    for (int c = 0; c < 10; c++) {
        tot[c] = s * num[c];
        tot[c] += __shfl_xor(tot[c], 16);
        tot[c] += __shfl_xor(tot[c], 32);
    }
    if (lane < 10) {
        float v = lane == 0 ? tot[0] : lane == 1 ? tot[1] : lane == 2 ? tot[2] :
                  lane == 3 ? tot[3] : lane == 4 ? tot[4] : lane == 5 ? tot[5] :
                  lane == 6 ? tot[6] : lane == 7 ? tot[7] : lane == 8 ? tot[8] : tot[9];
        if (is_hop0) {
            const ushort* vb = Vbf_all + (size_t)gw * 64 + lane;
            float vsum = bfs(vb[0]) + bfs(vb[16]) + bfs(vb[32]) + bfs(vb[48]);
            out[(size_t)gw * 10 + lane] = hopwise[0] * vsum + v;
        } else {
            out[(size_t)gw * 10 + lane] += v;
        }
    }
    if (write_next) {
        uint4 o;
        o.x = pk8<true>(A0[1].x, A0[1].y, pk8<false>(A0[0].x, A0[0].y, 0u));
        o.y = pk8<true>(A0[3].x, A0[3].y, pk8<false>(A0[2].x, A0[2].y, 0u));
        o.z = pk8<true>(A1[1].x, A1[1].y, pk8<false>(A1[0].x, A1[0].y, 0u));
        o.w = pk8<true>(A1[3].x, A1[3].y, pk8<false>(A1[2].x, A1[2].y, 0u));
        Mq4n[(size_t)gw * 64 + lane] = o;
        Mrun[(size_t)gw * 64 + lane] =
            pk8<true>(A1[4].x, A1[4].y, pk8<false>(A0[4].x, A0[4].y, 0u));
        uint kw = pk8<false>(kA.x, kA.y, 0u);
        K8n[(size_t)gw * 64 + lane] = (ushort)(kw & 0xFFFF);
    }
}

// -------- per-edge fp8 accumulate (packed f32x2) --------
__device__ __forceinline__ void edge_acc(f32x2 A0[5], f32x2 A1[5], f32x2& kA,
                                         uint4 mq, uint mr, uint kk) {
    A0[0] += upk8<false>(mq.x);
    A0[1] += upk8<true>(mq.x);
    A0[2] += upk8<false>(mq.y);
    A0[3] += upk8<true>(mq.y);
    A1[0] += upk8<false>(mq.z);
    A1[1] += upk8<true>(mq.z);
    A1[2] += upk8<false>(mq.w);
    A1[3] += upk8<true>(mq.w);
    A0[4] += upk8<false>(mr);
    A1[4] += upk8<true>(mr);
    kA += upk8<false>(kk);
}

// -------- fused hop 0: all heads; gather fp8 K0 row + per-head bf16 V row --------
__global__ __launch_bounds__(256) void aggf0_kernel(const ushort* __restrict__ K8c,
                                                    const ushort* __restrict__ Vbf,
                                                    const float* __restrict__ Qp,
                                                    float* __restrict__ out,
                                                    uint4* __restrict__ Mq4n, uint* __restrict__ Mrun,
                                                    ushort* __restrict__ K8n,
                                                    const int* __restrict__ rowptr,
                                                    const int* __restrict__ srows,
                                                    const float* __restrict__ hopwise,
                                                    const float* __restrict__ headwise) {
    int gw = (blockIdx.x * 256 + threadIdx.x) >> 6;
    int lane = threadIdx.x & 63;
    int h = lane >> 4;
    int beg = rowptr[gw], end = rowptr[gw + 1];
    f32x2 A0[5], A1[5], kA = f32x2{0.f, 0.f};
#pragma unroll
    for (int j = 0; j < 5; j++) { A0[j] = f32x2{0.f, 0.f}; A1[j] = f32x2{0.f, 0.f}; }
    int e = beg;
    for (; e + 1 < end; e += 2) {
        int s0 = srows[e], s1 = srows[e + 1];
        uint k0w = K8c[(size_t)s0 * 64 + lane];
        uint k1w = K8c[(size_t)s1 * 64 + lane];
        const ushort* vb0 = Vbf + (size_t)s0 * 64 + h * 16;
        const ushort* vb1 = Vbf + (size_t)s1 * 64 + h * 16;
        uint4 v40 = *(const uint4*)vb0; uint v10 = *(const uint*)(vb0 + 8);
        uint4 v41 = *(const uint4*)vb1; uint v11 = *(const uint*)(vb1 + 8);
        f32x2 kk0 = upk8<false>(k0w);   // {K0/16 p0, K0/16 p1}
        f32x2 kk1 = upk8<false>(k1w);
        kA += kk0 + kk1;
        f32x2 V0[5] = {bf2(v40.x), bf2(v40.y), bf2(v40.z), bf2(v40.w), bf2(v10)};
        f32x2 V1[5] = {bf2(v41.x), bf2(v41.y), bf2(v41.z), bf2(v41.w), bf2(v11)};
        f32x2 k00 = f32x2{kk0.x, kk0.x}, k01 = f32x2{kk0.y, kk0.y};
        f32x2 k10 = f32x2{kk1.x, kk1.x}, k11 = f32x2{kk1.y, kk1.y};
#pragma unroll
        for (int j = 0; j < 5; j++) {
            A0[j] += k00 * V0[j] + k10 * V1[j];
            A1[j] += k01 * V0[j] + k11 * V1[j];
        }
    }
    for (; e < end; ++e) {
        int s0 = srows[e];
        uint k0w = K8c[(size_t)s0 * 64 + lane];
        const ushort* vb0 = Vbf + (size_t)s0 * 64 + h * 16;
        uint4 v40 = *(const uint4*)vb0; uint v10 = *(const uint*)(vb0 + 8);
        f32x2 kk0 = upk8<false>(k0w);
        kA += kk0;
        f32x2 V0[5] = {bf2(v40.x), bf2(v40.y), bf2(v40.z), bf2(v40.w), bf2(v10)};
        f32x2 k00 = f32x2{kk0.x, kk0.x}, k01 = f32x2{kk0.y, kk0.y};
#pragma unroll
        for (int j = 0; j < 5; j++) {
            A0[j] += k00 * V0[j];
            A1[j] += k01 * V0[j];
        }
    }
    fused_epilog(A0, A1, kA, gw, lane, Qp, out, Mq4n, Mrun, K8n,
                 hopwise, headwise, Vbf, 0, 1, 1);
}

// -------- fused hops >=1: per edge uint4 (M c0-7) + uint (M c8-9) + ushort (K) --------
__global__ __launch_bounds__(256) void aggf_kernel(const uint4* __restrict__ Mq4,
                                                   const uint* __restrict__ Mru,
                                                   const ushort* __restrict__ K8c,
                                                   const float* __restrict__ Qp,
                                                   float* __restrict__ out,
                                                   uint4* __restrict__ Mq4n, uint* __restrict__ Mrun,
                                                   ushort* __restrict__ K8n,
                                                   const int* __restrict__ rowptr,
                                                   const int* __restrict__ srows,
                                                   const float* __restrict__ hopwise,
                                                   const float* __restrict__ headwise,
                                                   int hop, int write_next) {
    int gw = (blockIdx.x * 256 + threadIdx.x) >> 6;
    int lane = threadIdx.x & 63;
    int beg = rowptr[gw], end = rowptr[gw + 1];
    f32x2 A0[5], A1[5], kA = f32x2{0.f, 0.f};
#pragma unroll
    for (int j = 0; j < 5; j++) { A0[j] = f32x2{0.f, 0.f}; A1[j] = f32x2{0.f, 0.f}; }
    int e = beg;
    for (; e + 3 < end; e += 4) {
        int s0 = srows[e], s1 = srows[e + 1], s2 = srows[e + 2], s3 = srows[e + 3];
        uint4 m0 = Mq4[(size_t)s0 * 64 + lane];
        uint4 m1 = Mq4[(size_t)s1 * 64 + lane];
        uint4 m2 = Mq4[(size_t)s2 * 64 + lane];
        uint4 m3 = Mq4[(size_t)s3 * 64 + lane];
        uint r0 = Mru[(size_t)s0 * 64 + lane];
        uint r1 = Mru[(size_t)s1 * 64 + lane];
        uint r2 = Mru[(size_t)s2 * 64 + lane];
        uint r3 = Mru[(size_t)s3 * 64 + lane];
        uint k0 = K8c[(size_t)s0 * 64 + lane];
        uint k1 = K8c[(size_t)s1 * 64 + lane];
        uint k2 = K8c[(size_t)s2 * 64 + lane];
        uint k3 = K8c[(size_t)s3 * 64 + lane];
        edge_acc(A0, A1, kA, m0, r0, k0);
        edge_acc(A0, A1, kA, m1, r1, k1);
        edge_acc(A0, A1, kA, m2, r2, k2);
        edge_acc(A0, A1, kA, m3, r3, k3);
    }
    for (; e < end; ++e) {
        int s0 = srows[e];
        uint4 m0 = Mq4[(size_t)s0 * 64 + lane];
        uint r0 = Mru[(size_t)s0 * 64 + lane];
        uint k0 = K8c[(size_t)s0 * 64 + lane];
        edge_acc(A0, A1, kA, m0, r0, k0);
    }
    fused_epilog(A0, A1, kA, gw, lane, Qp, out, Mq4n, Mrun, K8n,
                 hopwise, headwise, nullptr, hop, write_next, 0);
}

extern "C" void kernel_launch(void* const* d_in, const int* in_sizes, int n_in,
                              void* d_out, int out_size, void* d_ws, size_t ws_size,
                              hipStream_t stream) {
    const float* nf = (const float*)d_in[0];
    const int* ei = (const int*)d_in[1];
    const float* Wt = (const float*)d_in[2];
    const float* bt = (const float*)d_in[3];
    const float* Wq = (const float*)d_in[4];
    const float* bq = (const float*)d_in[5];
    const float* Wk = (const float*)d_in[6];
    const float* bk = (const float*)d_in[7];
    const float* Wv = (const float*)d_in[8];
    const float* bv = (const float*)d_in[9];
    const float* hopwise = (const float*)d_in[10];
    const float* headwise = (const float*)d_in[11];
    float* out = (float*)d_out;

    char* p = (char*)d_ws;
    auto alloc = [&](size_t bytes) {
        char* r = p;
        p += (bytes + 255) & ~(size_t)255;
        return r;
    };
    int* rowptr = (int*)alloc((NN + 4) * sizeof(int));
    int* cursor = (int*)alloc((NN + 4) * sizeof(int));
    int* bsum = (int*)alloc(NBLK * sizeof(int));
    int* boff = (int*)alloc(NBLK * sizeof(int));
    int* srows = (int*)alloc((size_t)NE * sizeof(int));
    int* flag = (int*)alloc(sizeof(int));
    ushort* Wtb = (ushort*)alloc(128 * 128 * sizeof(ushort));
    ushort* Wqkvb = (ushort*)alloc(304 * 128 * sizeof(ushort));
    float* Qp = (float*)alloc((size_t)NN * 128 * sizeof(float));             // 25.6 MB
    unsigned char* K8pp = (unsigned char*)alloc((size_t)NN * 128);           // 6.4 MB (K0/16 fp8)
    ushort* Vbf = (ushort*)alloc((size_t)NN * 64 * sizeof(ushort));          // 6.4 MB
    ushort* K8a = (ushort*)alloc((size_t)NN * 64 * sizeof(ushort));          // 6.4 MB (K1/16)
    uint4* Mq4a = (uint4*)alloc((size_t)NN * 64 * sizeof(uint4));            // 51.2 MB
    uint4* Mq4b = (uint4*)alloc((size_t)NN * 64 * sizeof(uint4));            // 51.2 MB
    uint* Mrua = (uint*)alloc((size_t)NN * 64 * sizeof(uint));               // 12.8 MB
    uint* Mrub = (uint*)alloc((size_t)NN * 64 * sizeof(uint));               // 12.8 MB
    // total ~176 MB. aliases over dead regions:
    ushort* xb = (ushort*)Mq4a;        // x bf16 dead before aggf0 writes Mq4a
    ushort* K8b = (ushort*)K8pp;       // K2 overwrites K0 (K0 last read by aggf0)

    detect_kernel<<<1, 64, 0, stream>>>(ei, flag);
    zero_kernel<<<(NN + 255) / 256, 256, 0, stream>>>(cursor, NN);
    hist_kernel<<<(NE + 255) / 256, 256, 0, stream>>>(ei, flag, cursor);
    bsum_kernel<<<NBLK, 256, 0, stream>>>(cursor, bsum);
    bscan_kernel<<<1, 64, 0, stream>>>(bsum, boff, rowptr);
    scanb_kernel<<<NBLK, 256, 0, stream>>>(cursor, boff, rowptr, cursor);
    scatter_kernel<<<(NE + 255) / 256, 256, 0, stream>>>(ei, flag, cursor, srows);

    wconv_kernel<<<(304 * 128 + 255) / 256, 256, 0, stream>>>(Wt, Wq, Wk, Wv, Wtb, Wqkvb);
    int nrb = (NN + 63) / 64;
    xm_kernel<<<dim3(nrb, 2), 256, 0, stream>>>(nf, Wtb, bt, xb);
    qkv_kernel<<<dim3(nrb, 3), 256, 0, stream>>>(xb, Wqkvb, bq, bk, bv, Qp, K8pp, Vbf);

    // hop 0: (K0/16, V) -> M1/16, K1/16 (+vinit fold); hop 1: -> M2/16, K2/16 ; hop 2: -> out only
    aggf0_kernel<<<NN / 4, 256, 0, stream>>>((const ushort*)K8pp, Vbf, Qp, out,
                                             Mq4a, Mrua, K8a,
                                             rowptr, srows, hopwise, headwise);
    aggf_kernel<<<NN / 4, 256, 0, stream>>>(Mq4a, Mrua, K8a, Qp, out, Mq4b, Mrub, K8b,
                                            rowptr, srows, hopwise, headwise, 1, 1);
    aggf_kernel<<<NN / 4, 256, 0, stream>>>(Mq4b, Mrub, K8b, Qp, out, Mq4a, Mrua, K8a,
                                            rowptr, srows, hopwise, headwise, 2, 0);
}

// Round 10
// 369.768 us; speedup vs baseline: 1.1096x; 1.0184x over previous
//
#include <hip/hip_runtime.h>
#include <hip/hip_bf16.h>

#define NN 50000
#define NE 400000
#define NF 128
#define HID 128
#define NH 4
#define HC 32
#define NC 10
#define KHOPS 3
#define NBLK ((NN + 1023) / 1024)   // 49

typedef unsigned int uint;
typedef unsigned short ushort;
typedef unsigned char uchar;
typedef __attribute__((ext_vector_type(8))) short bf16x8;
typedef __attribute__((ext_vector_type(4))) float f32x4;
typedef __attribute__((ext_vector_type(2))) float f32x2;

// -------- edge dtype detect: int64 (odd words all zero) vs int32 --------
__global__ void detect_kernel(const int* __restrict__ ei, int* __restrict__ flag) {
    int w = ei[2 * threadIdx.x + 1];
    unsigned long long b = __ballot(w != 0);
    if (threadIdx.x == 0) *flag = (b == 0ULL) ? 1 : 0;  // 1 => int64
}

__device__ __forceinline__ int edge_row(const int* ei, int is64, int e) {
    return is64 ? ei[2 * e] : ei[e];
}
__device__ __forceinline__ int edge_col(const int* ei, int is64, int e) {
    return is64 ? ei[2 * NE + 2 * e] : ei[NE + e];
}

__global__ void zero_kernel(int* __restrict__ p, int n) {
    int i = blockIdx.x * blockDim.x + threadIdx.x;
    if (i < n) p[i] = 0;
}

__global__ void hist_kernel(const int* __restrict__ ei, const int* __restrict__ flag,
                            int* __restrict__ counts) {
    int e = blockIdx.x * blockDim.x + threadIdx.x;
    if (e >= NE) return;
    int c = edge_col(ei, *flag, e);
    atomicAdd(&counts[c], 1);
}

// ---- hierarchical scan ----
__global__ __launch_bounds__(256) void bsum_kernel(const int* __restrict__ counts,
                                                   int* __restrict__ bsum) {
    int b = blockIdx.x, tid = threadIdx.x;
    int base = b * 1024 + tid * 4;
    int4 v = {0, 0, 0, 0};
    if (base < NN) v = *(const int4*)(counts + base);
    int s = v.x + v.y + v.z + v.w;
#pragma unroll
    for (int off = 32; off >= 1; off >>= 1) s += __shfl_xor(s, off);
    __shared__ int ws[4];
    int lane = tid & 63, w = tid >> 6;
    if (lane == 0) ws[w] = s;
    __syncthreads();
    if (tid == 0) bsum[b] = ws[0] + ws[1] + ws[2] + ws[3];
}

__global__ void bscan_kernel(const int* __restrict__ bsum, int* __restrict__ boff,
                             int* __restrict__ rowptr) {
    int lane = threadIdx.x;
    int v = (lane < NBLK) ? bsum[lane] : 0;
    int t = v;
#pragma unroll
    for (int off = 1; off < 64; off <<= 1) {
        int u = __shfl_up(t, off);
        if (lane >= off) t += u;
    }
    if (lane < NBLK) boff[lane] = t - v;
    if (lane == NBLK - 1) rowptr[NN] = t;
}

__global__ __launch_bounds__(256) void scanb_kernel(const int* __restrict__ counts,
                                                    const int* __restrict__ boff,
                                                    int* __restrict__ rowptr,
                                                    int* __restrict__ cursor) {
    int b = blockIdx.x, tid = threadIdx.x;
    int base = b * 1024 + tid * 4;
    int4 v = {0, 0, 0, 0};
    if (base < NN) v = *(const int4*)(counts + base);
    int s3 = v.x + v.y + v.z + v.w;
    int lane = tid & 63, w = tid >> 6;
    int t = s3;
#pragma unroll
    for (int off = 1; off < 64; off <<= 1) {
        int u = __shfl_up(t, off);
        if (lane >= off) t += u;
    }
    __shared__ int ws[4];
    if (lane == 63) ws[w] = t;
    __syncthreads();
    int wofs = boff[b];
    for (int i = 0; i < 4; i++) wofs += (i < w) ? ws[i] : 0;
    int excl = wofs + t - s3;
    if (base < NN) {
        int4 o;
        o.x = excl;
        o.y = excl + v.x;
        o.z = o.y + v.y;
        o.w = o.z + v.z;
        *(int4*)(rowptr + base) = o;
        *(int4*)(cursor + base) = o;
    }
}

__global__ void scatter_kernel(const int* __restrict__ ei, const int* __restrict__ flag,
                               int* __restrict__ cursor, int* __restrict__ srows) {
    int e = blockIdx.x * blockDim.x + threadIdx.x;
    if (e >= NE) return;
    int is64 = *flag;
    int r = edge_row(ei, is64, e);
    int c = edge_col(ei, is64, e);
    int pos = atomicAdd(&cursor[c], 1);
    srows[pos] = r;
}

// -------- bf16 helpers --------
__device__ __forceinline__ short bfbits(float f) {
    __hip_bfloat16 h = __float2bfloat16(f);
    return *reinterpret_cast<short*>(&h);
}
__device__ __forceinline__ ushort bfbitsu(float f) {
    __hip_bfloat16 h = __float2bfloat16(f);
    return *reinterpret_cast<ushort*>(&h);
}
__device__ __forceinline__ float bfs(ushort u) { return __uint_as_float(((uint)u) << 16); }
__device__ __forceinline__ f32x2 bf2(uint u) {
    return f32x2{__uint_as_float(u << 16), __uint_as_float(u & 0xFFFF0000u)};
}

// -------- fp8 e4m3 pack/unpack (HW cvt; word-select compile-time) --------
template<bool HI>
__device__ __forceinline__ uint pk8(float a, float b, uint old) {
    return __builtin_amdgcn_cvt_pk_fp8_f32(a, b, old, HI);
}
template<bool HI>
__device__ __forceinline__ f32x2 upk8(uint w) {
    return __builtin_amdgcn_cvt_pk_f32_fp8(w, HI);
}

// -------- weight convert: bf16, transposed [col][k] --------
__global__ void wconv_kernel(const float* __restrict__ Wt, const float* __restrict__ Wq,
                             const float* __restrict__ Wk, const float* __restrict__ Wv,
                             ushort* __restrict__ Wtb, ushort* __restrict__ Wqkvb) {
    int idx = blockIdx.x * 256 + threadIdx.x;
    if (idx < 128 * 128) {
        int c = idx >> 7, k = idx & 127;
        Wtb[c * 128 + k] = bfbitsu(Wt[k * 128 + c]);
    }
    if (idx < 304 * 128) {
        int c = idx >> 7, k = idx & 127;
        float w;
        if (c < 128) w = Wq[k * 128 + c];
        else if (c < 256) w = Wk[k * 128 + (c - 128)];
        else { int cv = c - 256; w = (cv < 40) ? Wv[k * 40 + cv] : 0.f; }
        Wqkvb[c * 128 + k] = bfbitsu(w);
    }
}

// -------- x = relu(nf @ Wt + bt), MFMA, column-split over gridDim.y --------
__global__ __launch_bounds__(256) void xm_kernel(const float* __restrict__ nf,
                                                 const ushort* __restrict__ Wtb,
                                                 const float* __restrict__ bt,
                                                 ushort* __restrict__ xb) {
    int wid = threadIdx.x >> 6, lane = threadIdx.x & 63;
    int row0 = blockIdx.x * 64 + wid * 16;
    int r = lane & 15, kg = lane >> 4;
    int ar = row0 + r;
    if (ar > NN - 1) ar = NN - 1;
    int ctbeg = blockIdx.y * 4;
    f32x4 acc[4];
#pragma unroll
    for (int ct = 0; ct < 4; ct++) acc[ct] = f32x4{0.f, 0.f, 0.f, 0.f};
#pragma unroll
    for (int ks = 0; ks < 4; ks++) {
        int k0 = ks * 32 + kg * 8;
        const float4* ap = (const float4*)(nf + (size_t)ar * 128 + k0);
        float4 a0 = ap[0], a1 = ap[1];
        bf16x8 af;
        af[0] = bfbits(a0.x); af[1] = bfbits(a0.y); af[2] = bfbits(a0.z); af[3] = bfbits(a0.w);
        af[4] = bfbits(a1.x); af[5] = bfbits(a1.y); af[6] = bfbits(a1.z); af[7] = bfbits(a1.w);
#pragma unroll
        for (int ct = 0; ct < 4; ct++) {
            bf16x8 bfr = *(const bf16x8*)(Wtb + (size_t)((ctbeg + ct) * 16 + r) * 128 + k0);
            acc[ct] = __builtin_amdgcn_mfma_f32_16x16x32_bf16(af, bfr, acc[ct], 0, 0, 0);
        }
    }
#pragma unroll
    for (int ct = 0; ct < 4; ct++) {
        int c = (ctbeg + ct) * 16 + r;
        float b = bt[c];
#pragma unroll
        for (int reg = 0; reg < 4; reg++) {
            int n = row0 + kg * 4 + reg;
            if (n < NN) {
                float z = acc[ct][reg] + b;
                xb[(size_t)n * 128 + c] = bfbitsu(fmaxf(z, 0.f));
            }
        }
    }
}

// -------- fused QKV; Q -> Qp f32 [n][128], K -> K0/16 fp8 [n][128], V -> bf16 [n][4][16] --------
template<int CTBEG, int NCT>
__device__ __forceinline__ void qkv_body(const ushort* __restrict__ xb,
                                         const ushort* __restrict__ Wqkvb,
                                         const float* __restrict__ bq,
                                         const float* __restrict__ bk,
                                         const float* __restrict__ bv,
                                         float* __restrict__ Qp,
                                         uchar* __restrict__ K8,
                                         ushort* __restrict__ Vbf,
                                         int row0, int r, int kg) {
    int ar = row0 + r;
    if (ar > NN - 1) ar = NN - 1;
    f32x4 acc[NCT];
#pragma unroll
    for (int ct = 0; ct < NCT; ct++) acc[ct] = f32x4{0.f, 0.f, 0.f, 0.f};
#pragma unroll
    for (int ks = 0; ks < 4; ks++) {
        int k0 = ks * 32 + kg * 8;
        bf16x8 af = *(const bf16x8*)(xb + (size_t)ar * 128 + k0);
#pragma unroll
        for (int ct = 0; ct < NCT; ct++) {
            bf16x8 bfr = *(const bf16x8*)(Wqkvb + (size_t)((CTBEG + ct) * 16 + r) * 128 + k0);
            acc[ct] = __builtin_amdgcn_mfma_f32_16x16x32_bf16(af, bfr, acc[ct], 0, 0, 0);
        }
    }
#pragma unroll
    for (int ct = 0; ct < NCT; ct++) {
        int c = (CTBEG + ct) * 16 + r;
        float bias;
        if (c < 128) bias = bq[c];
        else if (c < 256) bias = bk[c - 128];
        else { int cv = c - 256; bias = (cv < 40) ? bv[cv] : 0.f; }
#pragma unroll
        for (int reg = 0; reg < 4; reg++) {
            int n = row0 + kg * 4 + reg;
            if (n >= NN) continue;
            float z = acc[ct][reg] + bias;
            if (c < 128) {
                float q = z > 0.f ? 1.f + z : __expf(z);
                Qp[(size_t)n * 128 + c] = q;
            } else if (c < 256) {
                int cc = c - 128;
                float kv = (z > 0.f ? 1.f + z : __expf(z)) * 0.0625f;  // K0/16
                uint w = pk8<false>(kv, 0.f, 0u);
                K8[(size_t)n * 128 + cc] = (uchar)(w & 0xFF);
            } else {
                int cv = c - 256;
                if (cv < 40) {
                    int hh = cv / 10, cc = cv - hh * 10;
                    Vbf[(size_t)n * 64 + hh * 16 + cc] = bfbitsu(z);
                }
            }
        }
    }
}

__global__ __launch_bounds__(256) void qkv_kernel(const ushort* __restrict__ xb,
                                                  const ushort* __restrict__ Wqkvb,
                                                  const float* __restrict__ bq,
                                                  const float* __restrict__ bk,
                                                  const float* __restrict__ bv,
                                                  float* __restrict__ Qp,
                                                  uchar* __restrict__ K8,
                                                  ushort* __restrict__ Vbf) {
    int wid = threadIdx.x >> 6, lane = threadIdx.x & 63;
    int row0 = blockIdx.x * 64 + wid * 16;
    int r = lane & 15, kg = lane >> 4;
    if (blockIdx.y == 0)
        qkv_body<0, 8>(xb, Wqkvb, bq, bk, bv, Qp, K8, Vbf, row0, r, kg);
    else if (blockIdx.y == 1)
        qkv_body<8, 8>(xb, Wqkvb, bq, bk, bv, Qp, K8, Vbf, row0, r, kg);
    else
        qkv_body<16, 3>(xb, Wqkvb, bq, bk, bv, Qp, K8, Vbf, row0, r, kg);
}

// ==================== hop 0: 1 wave/node (2 pairs/lane) ====================
// Writes next-M in the SPLIT layout consumed by aggf:
//   Mq2[(2n+hp)*64 + lp]  uint2  (c0-7 fp8 of pair lp of half hp)
//   Mr2[(2n+hp)*64 + lp]  ushort (c8-9)
//   K82[(2n+hp)*64 + lp]  uchar  (K)
__global__ __launch_bounds__(256) void aggf0_kernel(const ushort* __restrict__ K8c,
                                                    const ushort* __restrict__ Vbf,
                                                    const float* __restrict__ Qp,
                                                    float* __restrict__ out,
                                                    uint2* __restrict__ Mq2n, ushort* __restrict__ Mr2n,
                                                    uchar* __restrict__ K82n,
                                                    const int* __restrict__ rowptr,
                                                    const int* __restrict__ srows,
                                                    const float* __restrict__ hopwise,
                                                    const float* __restrict__ headwise) {
    int gw = (blockIdx.x * 256 + threadIdx.x) >> 6;
    int lane = threadIdx.x & 63;
    int h = lane >> 4;
    int beg = rowptr[gw], end = rowptr[gw + 1];
    f32x2 A0[5], A1[5], kA = f32x2{0.f, 0.f};
#pragma unroll
    for (int j = 0; j < 5; j++) { A0[j] = f32x2{0.f, 0.f}; A1[j] = f32x2{0.f, 0.f}; }
    int e = beg;
    for (; e + 1 < end; e += 2) {
        int s0 = srows[e], s1 = srows[e + 1];
        uint k0w = K8c[(size_t)s0 * 64 + lane];
        uint k1w = K8c[(size_t)s1 * 64 + lane];
        const ushort* vb0 = Vbf + (size_t)s0 * 64 + h * 16;
        const ushort* vb1 = Vbf + (size_t)s1 * 64 + h * 16;
        uint4 v40 = *(const uint4*)vb0; uint v10 = *(const uint*)(vb0 + 8);
        uint4 v41 = *(const uint4*)vb1; uint v11 = *(const uint*)(vb1 + 8);
        f32x2 kk0 = upk8<false>(k0w);
        f32x2 kk1 = upk8<false>(k1w);
        kA += kk0 + kk1;
        f32x2 V0[5] = {bf2(v40.x), bf2(v40.y), bf2(v40.z), bf2(v40.w), bf2(v10)};
        f32x2 V1[5] = {bf2(v41.x), bf2(v41.y), bf2(v41.z), bf2(v41.w), bf2(v11)};
        f32x2 k00 = f32x2{kk0.x, kk0.x}, k01 = f32x2{kk0.y, kk0.y};
        f32x2 k10 = f32x2{kk1.x, kk1.x}, k11 = f32x2{kk1.y, kk1.y};
#pragma unroll
        for (int j = 0; j < 5; j++) {
            A0[j] += k00 * V0[j] + k10 * V1[j];
            A1[j] += k01 * V0[j] + k11 * V1[j];
        }
    }
    for (; e < end; ++e) {
        int s0 = srows[e];
        uint k0w = K8c[(size_t)s0 * 64 + lane];
        const ushort* vb0 = Vbf + (size_t)s0 * 64 + h * 16;
        uint4 v40 = *(const uint4*)vb0; uint v10 = *(const uint*)(vb0 + 8);
        f32x2 kk0 = upk8<false>(k0w);
        kA += kk0;
        f32x2 V0[5] = {bf2(v40.x), bf2(v40.y), bf2(v40.z), bf2(v40.w), bf2(v10)};
        f32x2 k00 = f32x2{kk0.x, kk0.x}, k01 = f32x2{kk0.y, kk0.y};
#pragma unroll
        for (int j = 0; j < 5; j++) {
            A0[j] += k00 * V0[j];
            A1[j] += k01 * V0[j];
        }
    }
    // ---- epilog (hop 0): H readout + vinit fold, write out; write split-M ----
    int p0 = lane * 2;
    float2 q = *(const float2*)(Qp + (size_t)gw * 128 + p0);
    float num[10];
#pragma unroll
    for (int j = 0; j < 5; j++) {
        num[2 * j] = q.x * A0[j].x + q.y * A1[j].x;
        num[2 * j + 1] = q.x * A0[j].y + q.y * A1[j].y;
    }
    float den = q.x * kA.x + q.y * kA.y;
#pragma unroll
    for (int off = 8; off >= 1; off >>= 1) {
#pragma unroll
        for (int c = 0; c < 10; c++) num[c] += __shfl_xor(num[c], off);
        den += __shfl_xor(den, off);
    }
    float e0 = __expf(headwise[0 * KHOPS + 0]);
    float e1 = __expf(headwise[1 * KHOPS + 0]);
    float e2 = __expf(headwise[2 * KHOPS + 0]);
    float e3 = __expf(headwise[3 * KHOPS + 0]);
    float eh = (h == 0) ? e0 : (h == 1) ? e1 : (h == 2) ? e2 : e3;
    float gamma = hopwise[1] * eh / (e0 + e1 + e2 + e3);
    float s = gamma / (den + 6.25e-7f);
    float tot[10];
#pragma unroll
    for (int c = 0; c < 10; c++) {
        tot[c] = s * num[c];
        tot[c] += __shfl_xor(tot[c], 16);
        tot[c] += __shfl_xor(tot[c], 32);
    }
    if (lane < 10) {
        float v = lane == 0 ? tot[0] : lane == 1 ? tot[1] : lane == 2 ? tot[2] :
                  lane == 3 ? tot[3] : lane == 4 ? tot[4] : lane == 5 ? tot[5] :
                  lane == 6 ? tot[6] : lane == 7 ? tot[7] : lane == 8 ? tot[8] : tot[9];
        const ushort* vb = Vbf + (size_t)gw * 64 + lane;
        float vsum = bfs(vb[0]) + bfs(vb[16]) + bfs(vb[32]) + bfs(vb[48]);
        out[(size_t)gw * 10 + lane] = hopwise[0] * vsum + v;
    }
    // split-layout write: lane owns pairs p0,p0+1 of head h; half hp=h>>1, in-half lane lp
    {
        int R = 2 * gw + (lane >> 5);
        int lp = ((lane >> 4) & 1) * 32 + 2 * (lane & 15);
        uint4 o;
        o.x = pk8<true>(A0[1].x, A0[1].y, pk8<false>(A0[0].x, A0[0].y, 0u));
        o.y = pk8<true>(A0[3].x, A0[3].y, pk8<false>(A0[2].x, A0[2].y, 0u));
        o.z = pk8<true>(A1[1].x, A1[1].y, pk8<false>(A1[0].x, A1[0].y, 0u));
        o.w = pk8<true>(A1[3].x, A1[3].y, pk8<false>(A1[2].x, A1[2].y, 0u));
        *(uint4*)(Mq2n + (size_t)R * 64 + lp) = o;
        uint rw = pk8<true>(A1[4].x, A1[4].y, pk8<false>(A0[4].x, A0[4].y, 0u));
        *(uint*)(Mr2n + (size_t)R * 64 + lp) = rw;
        uint kw = pk8<false>(kA.x, kA.y, 0u);
        *(ushort*)(K82n + (size_t)R * 64 + lp) = (ushort)(kw & 0xFFFF);
    }
}

// ==================== hops >=1: 2 waves/node (1 pair/lane) ====================
__device__ __forceinline__ void edge_acc2(f32x2 A[5], float& kA, uint2 m, ushort r, uchar k) {
    A[0] += upk8<false>(m.x);
    A[1] += upk8<true>(m.x);
    A[2] += upk8<false>(m.y);
    A[3] += upk8<true>(m.y);
    A[4] += upk8<false>((uint)r);
    kA += upk8<false>((uint)k).x;
}

__global__ __launch_bounds__(256) void aggf_kernel(const uint2* __restrict__ Mq2,
                                                   const ushort* __restrict__ Mr2,
                                                   const uchar* __restrict__ K82,
                                                   const float* __restrict__ Qp,
                                                   float* __restrict__ out,
                                                   uint2* __restrict__ Mq2n, ushort* __restrict__ Mr2n,
                                                   uchar* __restrict__ K82n,
                                                   const int* __restrict__ rowptr,
                                                   const int* __restrict__ srows,
                                                   const float* __restrict__ hopwise,
                                                   const float* __restrict__ headwise,
                                                   int hop, int write_next) {
    int gwv = (blockIdx.x * 256 + threadIdx.x) >> 6;  // wave id
    int gw = gwv >> 1;                                // node
    int hp = gwv & 1;                                 // head-pair half
    int lane = threadIdx.x & 63;
    int beg = rowptr[gw], end = rowptr[gw + 1];
    f32x2 A[5];
    float kA = 0.f;
#pragma unroll
    for (int j = 0; j < 5; j++) A[j] = f32x2{0.f, 0.f};
    int e = beg;
    for (; e + 3 < end; e += 4) {
        int s0 = srows[e], s1 = srows[e + 1], s2 = srows[e + 2], s3 = srows[e + 3];
        size_t b0 = (size_t)(2 * s0 + hp) * 64 + lane;
        size_t b1 = (size_t)(2 * s1 + hp) * 64 + lane;
        size_t b2 = (size_t)(2 * s2 + hp) * 64 + lane;
        size_t b3 = (size_t)(2 * s3 + hp) * 64 + lane;
        uint2 m0 = Mq2[b0], m1 = Mq2[b1], m2 = Mq2[b2], m3 = Mq2[b3];
        ushort r0 = Mr2[b0], r1 = Mr2[b1], r2 = Mr2[b2], r3 = Mr2[b3];
        uchar k0 = K82[b0], k1 = K82[b1], k2 = K82[b2], k3 = K82[b3];
        edge_acc2(A, kA, m0, r0, k0);
        edge_acc2(A, kA, m1, r1, k1);
        edge_acc2(A, kA, m2, r2, k2);
        edge_acc2(A, kA, m3, r3, k3);
    }
    for (; e < end; ++e) {
        int s0 = srows[e];
        size_t b0 = (size_t)(2 * s0 + hp) * 64 + lane;
        edge_acc2(A, kA, Mq2[b0], Mr2[b0], K82[b0]);
    }
    // ---- epilog: reduce over i within 32-lane head group ----
    float q = Qp[(size_t)gw * 128 + hp * 64 + lane];
    float num[10];
#pragma unroll
    for (int j = 0; j < 5; j++) {
        num[2 * j] = q * A[j].x;
        num[2 * j + 1] = q * A[j].y;
    }
    float den = q * kA;
#pragma unroll
    for (int off = 16; off >= 1; off >>= 1) {
#pragma unroll
        for (int c = 0; c < 10; c++) num[c] += __shfl_xor(num[c], off);
        den += __shfl_xor(den, off);
    }
    float e0 = __expf(headwise[0 * KHOPS + hop]);
    float e1 = __expf(headwise[1 * KHOPS + hop]);
    float e2 = __expf(headwise[2 * KHOPS + hop]);
    float e3 = __expf(headwise[3 * KHOPS + hop]);
    int h = hp * 2 + (lane >> 5);
    float eh = (h == 0) ? e0 : (h == 1) ? e1 : (h == 2) ? e2 : e3;
    float gamma = hopwise[hop + 1] * eh / (e0 + e1 + e2 + e3);
    float s = gamma / (den + 6.25e-7f);
    float tot[10];
#pragma unroll
    for (int c = 0; c < 10; c++) {
        tot[c] = s * num[c];
        tot[c] += __shfl_xor(tot[c], 32);   // sum this wave's two heads
    }
    if (lane < 10) {
        float v = lane == 0 ? tot[0] : lane == 1 ? tot[1] : lane == 2 ? tot[2] :
                  lane == 3 ? tot[3] : lane == 4 ? tot[4] : lane == 5 ? tot[5] :
                  lane == 6 ? tot[6] : lane == 7 ? tot[7] : lane == 8 ? tot[8] : tot[9];
        atomicAdd(&out[(size_t)gw * 10 + lane], v);
    }
    if (write_next) {
        size_t b = (size_t)(2 * gw + hp) * 64 + lane;
        uint2 o;
        o.x = pk8<true>(A[1].x, A[1].y, pk8<false>(A[0].x, A[0].y, 0u));
        o.y = pk8<true>(A[3].x, A[3].y, pk8<false>(A[2].x, A[2].y, 0u));
        Mq2n[b] = o;
        uint rw = pk8<false>(A[4].x, A[4].y, 0u);
        Mr2n[b] = (ushort)(rw & 0xFFFF);
        uint kw = pk8<false>(kA, 0.f, 0u);
        K82n[b] = (uchar)(kw & 0xFF);
    }
}

extern "C" void kernel_launch(void* const* d_in, const int* in_sizes, int n_in,
                              void* d_out, int out_size, void* d_ws, size_t ws_size,
                              hipStream_t stream) {
    const float* nf = (const float*)d_in[0];
    const int* ei = (const int*)d_in[1];
    const float* Wt = (const float*)d_in[2];
    const float* bt = (const float*)d_in[3];
    const float* Wq = (const float*)d_in[4];
    const float* bq = (const float*)d_in[5];
    const float* Wk = (const float*)d_in[6];
    const float* bk = (const float*)d_in[7];
    const float* Wv = (const float*)d_in[8];
    const float* bv = (const float*)d_in[9];
    const float* hopwise = (const float*)d_in[10];
    const float* headwise = (const float*)d_in[11];
    float* out = (float*)d_out;

    char* p = (char*)d_ws;
    auto alloc = [&](size_t bytes) {
        char* r = p;
        p += (bytes + 255) & ~(size_t)255;
        return r;
    };
    int* rowptr = (int*)alloc((NN + 4) * sizeof(int));
    int* cursor = (int*)alloc((NN + 4) * sizeof(int));
    int* bsum = (int*)alloc(NBLK * sizeof(int));
    int* boff = (int*)alloc(NBLK * sizeof(int));
    int* srows = (int*)alloc((size_t)NE * sizeof(int));
    int* flag = (int*)alloc(sizeof(int));
    ushort* Wtb = (ushort*)alloc(128 * 128 * sizeof(ushort));
    ushort* Wqkvb = (ushort*)alloc(304 * 128 * sizeof(ushort));
    float* Qp = (float*)alloc((size_t)NN * 128 * sizeof(float));       // 25.6 MB
    uchar* K8pp = (uchar*)alloc((size_t)NN * 128);                     // 6.4 MB (K0/16 fp8)
    ushort* Vbf = (ushort*)alloc((size_t)NN * 64 * sizeof(ushort));    // 6.4 MB
    uchar* K82a = (uchar*)alloc((size_t)NN * 128);                     // 6.4 MB (K1/16 split)
    uint2* Mq2a = (uint2*)alloc((size_t)NN * 128 * sizeof(uint2));     // 51.2 MB
    uint2* Mq2b = (uint2*)alloc((size_t)NN * 128 * sizeof(uint2));     // 51.2 MB
    ushort* Mr2a = (ushort*)alloc((size_t)NN * 128 * sizeof(ushort));  // 12.8 MB
    ushort* Mr2b = (ushort*)alloc((size_t)NN * 128 * sizeof(ushort));  // 12.8 MB
    // total ~176 MB. aliases over dead regions:
    ushort* xb = (ushort*)Mq2a;    // x bf16 dead before aggf0 writes Mq2a
    uchar* K82b = K8pp;            // K2 overwrites K0 (K0 last read by aggf0)

    detect_kernel<<<1, 64, 0, stream>>>(ei, flag);
    zero_kernel<<<(NN + 255) / 256, 256, 0, stream>>>(cursor, NN);
    hist_kernel<<<(NE + 255) / 256, 256, 0, stream>>>(ei, flag, cursor);
    bsum_kernel<<<NBLK, 256, 0, stream>>>(cursor, bsum);
    bscan_kernel<<<1, 64, 0, stream>>>(bsum, boff, rowptr);
    scanb_kernel<<<NBLK, 256, 0, stream>>>(cursor, boff, rowptr, cursor);
    scatter_kernel<<<(NE + 255) / 256, 256, 0, stream>>>(ei, flag, cursor, srows);

    wconv_kernel<<<(304 * 128 + 255) / 256, 256, 0, stream>>>(Wt, Wq, Wk, Wv, Wtb, Wqkvb);
    int nrb = (NN + 63) / 64;
    xm_kernel<<<dim3(nrb, 2), 256, 0, stream>>>(nf, Wtb, bt, xb);
    qkv_kernel<<<dim3(nrb, 3), 256, 0, stream>>>(xb, Wqkvb, bq, bk, bv, Qp, K8pp, Vbf);

    // hop 0 (1 wave/node): (K0/16, V) -> split M1/16, K1/16; writes out (vinit fold)
    aggf0_kernel<<<NN / 4, 256, 0, stream>>>((const ushort*)K8pp, Vbf, Qp, out,
                                             Mq2a, Mr2a, K82a,
                                             rowptr, srows, hopwise, headwise);
    // hops 1-2 (2 waves/node): atomicAdd into out
    aggf_kernel<<<NN / 2, 256, 0, stream>>>(Mq2a, Mr2a, K82a, Qp, out,
                                            Mq2b, Mr2b, K82b,
                                            rowptr, srows, hopwise, headwise, 1, 1);
    aggf_kernel<<<NN / 2, 256, 0, stream>>>(Mq2b, Mr2b, K82b, Qp, out,
                                            Mq2a, Mr2a, K82a,
                                            rowptr, srows, hopwise, headwise, 2, 0);
}